// Round 1
// baseline (511.194 us; speedup 1.0000x reference)
//
#include <hip/hip_runtime.h>

// B=128 trajectories, N=20000 vars, M=85400 clauses, K=3 literals/clause.
// Inputs: v(B*N) f32, xl(B*M) f32, xs(B*M) f32, param(6) f32,
//         input_sign(B*M*K) f32, input_idx(B*M*K) i32
// Outputs concat: C(B*M), grad_v(B*N), dxl(B*M), dxs(B*M)  -- all f32

#define NMAX 20000     // grad accumulator only: 80KB LDS -> 2 blocks/CU (32 waves)
#define BPB  4         // clause-chunks (blocks) per batch element

// native clang vector types — required by __builtin_nontemporal_load/store
typedef int   int4v   __attribute__((ext_vector_type(4)));
typedef float float4v __attribute__((ext_vector_type(4)));

__device__ __forceinline__ void clause_math(
    float a0, float a1, float a2, float xlv, float xsv, float zeta,
    float& C, float& g0, float& g1, float& g2)
{
    // top-2 with jax.lax.top_k tie semantics (first occurrence wins argmax)
    int k0; float m0, m1;
    if (a0 >= a1) {
        if (a0 >= a2) { k0 = 0; m0 = a0; m1 = fmaxf(a1, a2); }
        else          { k0 = 2; m0 = a2; m1 = fmaxf(a0, a1); }
    } else {
        if (a1 >= a2) { k0 = 1; m0 = a1; m1 = fmaxf(a0, a2); }
        else          { k0 = 2; m0 = a2; m1 = fmaxf(a0, a1); }
    }
    C = (1.f - m0) * 0.5f;
    const float T2 = (1.f - m1) * 0.5f;
    const float gl = xlv * xsv;
    const float rC = C * ((1.f + zeta * xlv) * (1.f - xsv));
    g0 = (k0 == 0 ? T2 : C) * gl + (k0 == 0 ? rC : 0.f);
    g1 = (k0 == 1 ? T2 : C) * gl + (k0 == 1 ? rC : 0.f);
    g2 = (k0 == 2 ? T2 : C) * gl + (k0 == 2 ? rC : 0.f);
}

// ---------- fast path: grad in LDS (80KB), v via L1/L2, 2 blocks/CU ----------
__global__ __launch_bounds__(1024, 8) void or_priv3(
    const float* __restrict__ v,
    const float* __restrict__ xl,
    const float* __restrict__ xs,
    const float* __restrict__ param,
    const float* __restrict__ sign,
    const int*   __restrict__ idx,
    float* __restrict__ outC,
    float* __restrict__ outdxl,
    float* __restrict__ outdxs,
    float* __restrict__ partial,   // [BPB][B][N]
    int N, int M, int B, int chunk)
{
    __shared__ float sg[NMAX];   // grad accumulator only

    // XCD-chunked swizzle: dispatch round-robins blockIdx.x across the 8 XCDs,
    // so give each XCD a CONTIGUOUS range of work ids -> its resident blocks
    // cover ~16 consecutive b values (16 x 80KB of v = 1.3MB, fits 4MB L2).
    const int id  = blockIdx.x;            // 0 .. BPB*B-1  (512, multiple of 8)
    const int cpx = gridDim.x >> 3;        // work ids per XCD
    const int cid = (id & 7) * cpx + (id >> 3);
    const int b   = cid >> 2;              // BPB == 4
    const int j   = cid & 3;
    const int tid = threadIdx.x;

    // zero grad accumulator
    {
        float4v* sg4 = (float4v*)sg;
        const float4v z = {0.f, 0.f, 0.f, 0.f};
        const int n4 = N >> 2;
        for (int i = tid; i < n4; i += 1024) sg4[i] = z;
        for (int i = (n4 << 2) + tid; i < N; i += 1024) sg[i] = 0.f;
    }
    __syncthreads();

    const float alpha = param[0], beta = param[1], gamma = param[2];
    const float delta = param[3], eps  = param[4], zeta  = param[5];

    const float* __restrict__ vb = v + (size_t)b * N;   // read through L1/L2

    const int mstart = j * chunk;                 // chunk is a multiple of 4
    const int mend   = min(M, mstart + chunk);
    const int ngroups = (mend > mstart) ? ((mend - mstart + 3) >> 2) : 0;

    for (int g = tid; g < ngroups; g += 1024) {
        const int m0 = mstart + (g << 2);
        const size_t base = (size_t)b * M + m0;    // multiple of 4 -> 16B aligned

        if (m0 + 3 < mend) {
            const int4v*   __restrict__ ip = (const int4v*)(idx + base * 3);
            const float4v* __restrict__ sp = (const float4v*)(sign + base * 3);
            const int4v   ia = __builtin_nontemporal_load(ip + 0);
            const int4v   ib = __builtin_nontemporal_load(ip + 1);
            const int4v   ic = __builtin_nontemporal_load(ip + 2);
            const float4v sa = __builtin_nontemporal_load(sp + 0);
            const float4v sb = __builtin_nontemporal_load(sp + 1);
            const float4v sc = __builtin_nontemporal_load(sp + 2);
            const float4v xl4 = __builtin_nontemporal_load((const float4v*)(xl + base));
            const float4v xs4 = __builtin_nontemporal_load((const float4v*)(xs + base));

            const int   ii[12] = {ia.x, ia.y, ia.z, ia.w, ib.x, ib.y, ib.z, ib.w,
                                  ic.x, ic.y, ic.z, ic.w};
            const float ss[12] = {sa.x, sa.y, sa.z, sa.w, sb.x, sb.y, sb.z, sb.w,
                                  sc.x, sc.y, sc.z, sc.w};
            const float xlA[4] = {xl4.x, xl4.y, xl4.z, xl4.w};
            const float xsA[4] = {xs4.x, xs4.y, xs4.z, xs4.w};
            float Cv[4], dxlv[4], dxsv[4];

            #pragma unroll
            for (int c = 0; c < 4; ++c) {
                const int   i0 = ii[3*c], i1 = ii[3*c+1], i2 = ii[3*c+2];
                const float s0 = ss[3*c], s1 = ss[3*c+1], s2 = ss[3*c+2];
                const float a0 = vb[i0] * s0, a1 = vb[i1] * s1, a2 = vb[i2] * s2;
                float C, g0, g1, g2;
                clause_math(a0, a1, a2, xlA[c], xsA[c], zeta, C, g0, g1, g2);
                unsafeAtomicAdd(&sg[i0], -g0 * s0);
                unsafeAtomicAdd(&sg[i1], -g1 * s1);
                unsafeAtomicAdd(&sg[i2], -g2 * s2);
                Cv[c]   = C;
                dxlv[c] = -alpha * (C - delta);
                dxsv[c] = -beta * (xsA[c] + eps) * (C - gamma);
            }
            const float4v cv  = {Cv[0], Cv[1], Cv[2], Cv[3]};
            const float4v lv  = {dxlv[0], dxlv[1], dxlv[2], dxlv[3]};
            const float4v svo = {dxsv[0], dxsv[1], dxsv[2], dxsv[3]};
            __builtin_nontemporal_store(cv,  (float4v*)(outC + base));
            __builtin_nontemporal_store(lv,  (float4v*)(outdxl + base));
            __builtin_nontemporal_store(svo, (float4v*)(outdxs + base));
        } else {
            for (int m = m0; m < mend; ++m) {
                const size_t bm  = (size_t)b * M + m;
                const size_t bm3 = bm * 3;
                const int   i0 = idx[bm3 + 0], i1 = idx[bm3 + 1], i2 = idx[bm3 + 2];
                const float s0 = sign[bm3 + 0], s1 = sign[bm3 + 1], s2 = sign[bm3 + 2];
                const float a0 = vb[i0] * s0, a1 = vb[i1] * s1, a2 = vb[i2] * s2;
                const float xlv = xl[bm], xsv = xs[bm];
                float C, g0, g1, g2;
                clause_math(a0, a1, a2, xlv, xsv, zeta, C, g0, g1, g2);
                unsafeAtomicAdd(&sg[i0], -g0 * s0);
                unsafeAtomicAdd(&sg[i1], -g1 * s1);
                unsafeAtomicAdd(&sg[i2], -g2 * s2);
                outC[bm]   = C;
                outdxl[bm] = -alpha * (C - delta);
                outdxs[bm] = -beta * (xsv + eps) * (C - gamma);
            }
        }
    }
    __syncthreads();

    // flush grad accumulator to the per-(j,b) partial slab (coalesced float4)
    {
        float* __restrict__ pj = partial + ((size_t)j * B + b) * N;
        const float4v* sg4 = (const float4v*)sg;
        const int n4 = N >> 2;
        for (int i = tid; i < n4; i += 1024)
            __builtin_nontemporal_store(sg4[i], (float4v*)pj + i);
        for (int i = (n4 << 2) + tid; i < N; i += 1024) pj[i] = sg[i];
    }
}

__global__ __launch_bounds__(256) void reduce4(
    const float4v* __restrict__ p, float4v* __restrict__ out, int n4, int stride4)
{
    int i = blockIdx.x * 256 + threadIdx.x;
    const int gs = gridDim.x * 256;
    for (; i < n4; i += gs) {
        const float4v a = p[i];
        const float4v b = p[i + stride4];
        const float4v c = p[i + 2 * stride4];
        const float4v d = p[i + 3 * stride4];
        out[i] = a + b + c + d;
    }
}

// ---------- fallback path (round-1, global atomics) ----------
__global__ __launch_bounds__(256) void zero_f4(float4v* __restrict__ p, int n4) {
    int i = blockIdx.x * blockDim.x + threadIdx.x;
    int stride = gridDim.x * blockDim.x;
    const float4v z = {0.f, 0.f, 0.f, 0.f};
    for (; i < n4; i += stride) p[i] = z;
}

__global__ __launch_bounds__(256) void or_kernel(
    const float* __restrict__ v, const float* __restrict__ xl,
    const float* __restrict__ xs, const float* __restrict__ param,
    const float* __restrict__ sign, const int* __restrict__ idx,
    float* __restrict__ outC, float* __restrict__ gradv,
    float* __restrict__ outdxl, float* __restrict__ outdxs, int N, int M)
{
    const int m = blockIdx.x * blockDim.x + threadIdx.x;
    const int b = blockIdx.y;
    if (m >= M) return;
    const size_t bm = (size_t)b * M + m;
    const size_t bm3 = bm * 3;
    const int   i0 = idx[bm3 + 0], i1 = idx[bm3 + 1], i2 = idx[bm3 + 2];
    const float s0 = sign[bm3 + 0], s1 = sign[bm3 + 1], s2 = sign[bm3 + 2];
    const float* __restrict__ vb = v + (size_t)b * N;
    const float a0 = vb[i0] * s0, a1 = vb[i1] * s1, a2 = vb[i2] * s2;
    const float xlv = xl[bm], xsv = xs[bm];
    const float alpha = param[0], beta = param[1], gamma = param[2];
    const float delta = param[3], eps  = param[4], zeta  = param[5];

    float C, g0, g1, g2;
    clause_math(a0, a1, a2, xlv, xsv, zeta, C, g0, g1, g2);

    float* __restrict__ gb = gradv + (size_t)b * N;
    atomicAdd(&gb[i0], -g0 * s0);
    atomicAdd(&gb[i1], -g1 * s1);
    atomicAdd(&gb[i2], -g2 * s2);

    outC[bm]   = C;
    outdxl[bm] = -alpha * (C - delta);
    outdxs[bm] = -beta * (xsv + eps) * (C - gamma);
}

extern "C" void kernel_launch(void* const* d_in, const int* in_sizes, int n_in,
                              void* d_out, int out_size, void* d_ws, size_t ws_size,
                              hipStream_t stream) {
    const float* v     = (const float*)d_in[0];
    const float* xl    = (const float*)d_in[1];
    const float* xs    = (const float*)d_in[2];
    const float* param = (const float*)d_in[3];
    const float* sign  = (const float*)d_in[4];
    const int*   idx   = (const int*)d_in[5];

    const int B = 128;
    const int N = in_sizes[0] / B;   // 20000
    const int M = in_sizes[1] / B;   // 85400

    float* outC   = (float*)d_out;
    float* gradv  = outC   + (size_t)in_sizes[1];
    float* outdxl = gradv  + (size_t)in_sizes[0];
    float* outdxs = outdxl + (size_t)in_sizes[1];

    const size_t bn = (size_t)B * N;
    const size_t ws_need = (size_t)BPB * bn * sizeof(float);

    if (N <= NMAX && ws_size >= ws_need && (bn % 4) == 0 && (M % 4) == 0) {
        float* partial = (float*)d_ws;
        // chunk: multiple of 4 so every group's base is 16B-aligned
        const int chunk = (((M + BPB - 1) / BPB) + 3) & ~3;
        or_priv3<<<dim3(BPB * B), dim3(1024), 0, stream>>>(
            v, xl, xs, param, sign, idx, outC, outdxl, outdxs,
            (float*)partial, N, M, B, chunk);
        const int n4 = (int)(bn / 4);
        const int rblocks = min(2048, (n4 + 255) / 256);
        reduce4<<<dim3(rblocks), dim3(256), 0, stream>>>(
            (const float4v*)partial, (float4v*)gradv, n4, n4);
    } else {
        const int n4 = (int)(bn / 4);
        zero_f4<<<dim3((n4 + 255) / 256), dim3(256), 0, stream>>>((float4v*)gradv, n4);
        dim3 grid((M + 255) / 256, B);
        or_kernel<<<grid, dim3(256), 0, stream>>>(v, xl, xs, param, sign, idx,
                                                  outC, gradv, outdxl, outdxs, N, M);
    }
}

// Round 2
// 461.726 us; speedup vs baseline: 1.1071x; 1.1071x over previous
//
#include <hip/hip_runtime.h>

// B=128 trajectories, N=20000 vars, M=85400 clauses, K=3 literals/clause.
// Inputs: v(B*N) f32, xl(B*M) f32, xs(B*M) f32, param(6) f32,
//         input_sign(B*M*K) f32, input_idx(B*M*K) i32
// Outputs concat: C(B*M), grad_v(B*N), dxl(B*M), dxs(B*M)  -- all f32

#define NMAX 20000     // sv (80KB) + sg (80KB) = 160KB LDS -> 1 block/CU
#define BPB  2         // clause-chunks (blocks) per batch element -> grid 256 = 1/CU

// native clang vector types — required by __builtin_nontemporal_load/store
typedef int   int4v   __attribute__((ext_vector_type(4)));
typedef float float4v __attribute__((ext_vector_type(4)));

__device__ __forceinline__ void clause_math(
    float a0, float a1, float a2, float xlv, float xsv, float zeta,
    float& C, float& g0, float& g1, float& g2)
{
    // top-2 with jax.lax.top_k tie semantics (first occurrence wins argmax)
    int k0; float m0, m1;
    if (a0 >= a1) {
        if (a0 >= a2) { k0 = 0; m0 = a0; m1 = fmaxf(a1, a2); }
        else          { k0 = 2; m0 = a2; m1 = fmaxf(a0, a1); }
    } else {
        if (a1 >= a2) { k0 = 1; m0 = a1; m1 = fmaxf(a0, a2); }
        else          { k0 = 2; m0 = a2; m1 = fmaxf(a0, a1); }
    }
    C = (1.f - m0) * 0.5f;
    const float T2 = (1.f - m1) * 0.5f;
    const float gl = xlv * xsv;
    const float rC = C * ((1.f + zeta * xlv) * (1.f - xsv));
    g0 = (k0 == 0 ? T2 : C) * gl + (k0 == 0 ? rC : 0.f);
    g1 = (k0 == 1 ? T2 : C) * gl + (k0 == 1 ? rC : 0.f);
    g2 = (k0 == 2 ? T2 : C) * gl + (k0 == 2 ? rC : 0.f);
}

// ---------- fast path: v + grad in LDS, 1 block/CU, software-pipelined ----------
__global__ __launch_bounds__(1024, 4) void or_priv4(
    const float* __restrict__ v,
    const float* __restrict__ xl,
    const float* __restrict__ xs,
    const float* __restrict__ param,
    const float* __restrict__ sign,
    const int*   __restrict__ idx,
    float* __restrict__ outC,
    float* __restrict__ outdxl,
    float* __restrict__ outdxs,
    float* __restrict__ partial,   // [BPB][B][N]
    int N, int M, int B, int chunk)
{
    __shared__ float sv[NMAX];   // v slice for batch b (gathers stay in LDS — R1 lesson)
    __shared__ float sg[NMAX];   // grad accumulator

    // XCD swizzle: co-locate the BPB=2 blocks of each b on one XCD so the
    // second 80KB v-stage hits that XCD's L2. grid=256, multiple of 8.
    const int id  = blockIdx.x;
    const int cpx = gridDim.x >> 3;
    const int cid = ((gridDim.x & 7) == 0) ? ((id & 7) * cpx + (id >> 3)) : id;
    const int b   = cid >> 1;              // BPB == 2
    const int j   = cid & 1;
    const int tid = threadIdx.x;

    // stage v slice (coalesced float4, cached — 2nd block of pair hits L2) + zero grad
    {
        const float4v* __restrict__ v4 = (const float4v*)(v + (size_t)b * N);
        float4v* sv4 = (float4v*)sv;
        float4v* sg4 = (float4v*)sg;
        const int n4 = N >> 2;
        const float4v z = {0.f, 0.f, 0.f, 0.f};
        for (int i = tid; i < n4; i += 1024) {
            sv4[i] = v4[i];
            sg4[i] = z;
        }
        for (int i = (n4 << 2) + tid; i < N; i += 1024) {
            sv[i] = v[(size_t)b * N + i];
            sg[i] = 0.f;
        }
    }
    __syncthreads();

    const float alpha = param[0], beta = param[1], gamma = param[2];
    const float delta = param[3], eps  = param[4], zeta  = param[5];

    const int mstart = j * chunk;                 // chunk is a multiple of 4
    const int mend   = min(M, mstart + chunk);
    const int mlen   = mend - mstart;

    if (mlen > 0 && (mlen & 3) == 0) {
        // all groups full: 1-deep software pipeline (prefetch next group's
        // streaming loads while computing the current one)
        const int ngroups = mlen >> 2;
        int g = tid;
        int4v   ia = {}, ib = {}, ic = {};
        float4v sa = {}, sb = {}, sc = {}, xl4 = {}, xs4 = {};
        if (g < ngroups) {
            const size_t base = (size_t)b * M + mstart + ((size_t)g << 2);
            const int4v*   __restrict__ ip = (const int4v*)(idx + base * 3);
            const float4v* __restrict__ sp = (const float4v*)(sign + base * 3);
            ia = __builtin_nontemporal_load(ip + 0);
            ib = __builtin_nontemporal_load(ip + 1);
            ic = __builtin_nontemporal_load(ip + 2);
            sa = __builtin_nontemporal_load(sp + 0);
            sb = __builtin_nontemporal_load(sp + 1);
            sc = __builtin_nontemporal_load(sp + 2);
            xl4 = __builtin_nontemporal_load((const float4v*)(xl + base));
            xs4 = __builtin_nontemporal_load((const float4v*)(xs + base));
        }
        for (; g < ngroups; g += 1024) {
            const int gn = g + 1024;
            int4v   ia2 = {}, ib2 = {}, ic2 = {};
            float4v sa2 = {}, sb2 = {}, sc2 = {}, xl42 = {}, xs42 = {};
            if (gn < ngroups) {
                const size_t basen = (size_t)b * M + mstart + ((size_t)gn << 2);
                const int4v*   __restrict__ ipn = (const int4v*)(idx + basen * 3);
                const float4v* __restrict__ spn = (const float4v*)(sign + basen * 3);
                ia2 = __builtin_nontemporal_load(ipn + 0);
                ib2 = __builtin_nontemporal_load(ipn + 1);
                ic2 = __builtin_nontemporal_load(ipn + 2);
                sa2 = __builtin_nontemporal_load(spn + 0);
                sb2 = __builtin_nontemporal_load(spn + 1);
                sc2 = __builtin_nontemporal_load(spn + 2);
                xl42 = __builtin_nontemporal_load((const float4v*)(xl + basen));
                xs42 = __builtin_nontemporal_load((const float4v*)(xs + basen));
            }

            const size_t base = (size_t)b * M + mstart + ((size_t)g << 2);
            const int   ii[12] = {ia.x, ia.y, ia.z, ia.w, ib.x, ib.y, ib.z, ib.w,
                                  ic.x, ic.y, ic.z, ic.w};
            const float ss[12] = {sa.x, sa.y, sa.z, sa.w, sb.x, sb.y, sb.z, sb.w,
                                  sc.x, sc.y, sc.z, sc.w};
            const float xlA[4] = {xl4.x, xl4.y, xl4.z, xl4.w};
            const float xsA[4] = {xs4.x, xs4.y, xs4.z, xs4.w};
            float Cv[4], dxlv[4], dxsv[4];

            #pragma unroll
            for (int c = 0; c < 4; ++c) {
                const int   i0 = ii[3*c], i1 = ii[3*c+1], i2 = ii[3*c+2];
                const float s0 = ss[3*c], s1 = ss[3*c+1], s2 = ss[3*c+2];
                const float a0 = sv[i0] * s0, a1 = sv[i1] * s1, a2 = sv[i2] * s2;
                float C, g0, g1, g2;
                clause_math(a0, a1, a2, xlA[c], xsA[c], zeta, C, g0, g1, g2);
                unsafeAtomicAdd(&sg[i0], -g0 * s0);
                unsafeAtomicAdd(&sg[i1], -g1 * s1);
                unsafeAtomicAdd(&sg[i2], -g2 * s2);
                Cv[c]   = C;
                dxlv[c] = -alpha * (C - delta);
                dxsv[c] = -beta * (xsA[c] + eps) * (C - gamma);
            }
            const float4v cv  = {Cv[0], Cv[1], Cv[2], Cv[3]};
            const float4v lv  = {dxlv[0], dxlv[1], dxlv[2], dxlv[3]};
            const float4v svo = {dxsv[0], dxsv[1], dxsv[2], dxsv[3]};
            __builtin_nontemporal_store(cv,  (float4v*)(outC + base));
            __builtin_nontemporal_store(lv,  (float4v*)(outdxl + base));
            __builtin_nontemporal_store(svo, (float4v*)(outdxs + base));

            // rotate pipeline registers
            ia = ia2; ib = ib2; ic = ic2;
            sa = sa2; sb = sb2; sc = sc2;
            xl4 = xl42; xs4 = xs42;
        }
    } else {
        // ragged tail fallback (not hit for M%4==0 shapes)
        for (int m = mstart + tid; m < mend; m += 1024) {
            const size_t bm  = (size_t)b * M + m;
            const size_t bm3 = bm * 3;
            const int   i0 = idx[bm3 + 0], i1 = idx[bm3 + 1], i2 = idx[bm3 + 2];
            const float s0 = sign[bm3 + 0], s1 = sign[bm3 + 1], s2 = sign[bm3 + 2];
            const float a0 = sv[i0] * s0, a1 = sv[i1] * s1, a2 = sv[i2] * s2;
            const float xlv = xl[bm], xsv = xs[bm];
            float C, g0, g1, g2;
            clause_math(a0, a1, a2, xlv, xsv, zeta, C, g0, g1, g2);
            unsafeAtomicAdd(&sg[i0], -g0 * s0);
            unsafeAtomicAdd(&sg[i1], -g1 * s1);
            unsafeAtomicAdd(&sg[i2], -g2 * s2);
            outC[bm]   = C;
            outdxl[bm] = -alpha * (C - delta);
            outdxs[bm] = -beta * (xsv + eps) * (C - gamma);
        }
    }
    __syncthreads();

    // flush grad accumulator to the per-(j,b) partial slab.
    // Plain (cached) stores: reduce2 can then hit L2/L3 instead of HBM.
    {
        float* __restrict__ pj = partial + ((size_t)j * B + b) * N;
        const float4v* sg4 = (const float4v*)sg;
        const int n4 = N >> 2;
        for (int i = tid; i < n4; i += 1024)
            ((float4v*)pj)[i] = sg4[i];
        for (int i = (n4 << 2) + tid; i < N; i += 1024) pj[i] = sg[i];
    }
}

__global__ __launch_bounds__(256) void reduce2(
    const float4v* __restrict__ p, float4v* __restrict__ out, int n4, int stride4)
{
    int i = blockIdx.x * 256 + threadIdx.x;
    const int gs = gridDim.x * 256;
    for (; i < n4; i += gs) {
        const float4v a = p[i];
        const float4v b = p[i + stride4];
        out[i] = a + b;
    }
}

// ---------- fallback path (round-1, global atomics) ----------
__global__ __launch_bounds__(256) void zero_f4(float4v* __restrict__ p, int n4) {
    int i = blockIdx.x * blockDim.x + threadIdx.x;
    int stride = gridDim.x * blockDim.x;
    const float4v z = {0.f, 0.f, 0.f, 0.f};
    for (; i < n4; i += stride) p[i] = z;
}

__global__ __launch_bounds__(256) void or_kernel(
    const float* __restrict__ v, const float* __restrict__ xl,
    const float* __restrict__ xs, const float* __restrict__ param,
    const float* __restrict__ sign, const int* __restrict__ idx,
    float* __restrict__ outC, float* __restrict__ gradv,
    float* __restrict__ outdxl, float* __restrict__ outdxs, int N, int M)
{
    const int m = blockIdx.x * blockDim.x + threadIdx.x;
    const int b = blockIdx.y;
    if (m >= M) return;
    const size_t bm = (size_t)b * M + m;
    const size_t bm3 = bm * 3;
    const int   i0 = idx[bm3 + 0], i1 = idx[bm3 + 1], i2 = idx[bm3 + 2];
    const float s0 = sign[bm3 + 0], s1 = sign[bm3 + 1], s2 = sign[bm3 + 2];
    const float* __restrict__ vb = v + (size_t)b * N;
    const float a0 = vb[i0] * s0, a1 = vb[i1] * s1, a2 = vb[i2] * s2;
    const float xlv = xl[bm], xsv = xs[bm];
    const float alpha = param[0], beta = param[1], gamma = param[2];
    const float delta = param[3], eps  = param[4], zeta  = param[5];

    float C, g0, g1, g2;
    clause_math(a0, a1, a2, xlv, xsv, zeta, C, g0, g1, g2);

    float* __restrict__ gb = gradv + (size_t)b * N;
    atomicAdd(&gb[i0], -g0 * s0);
    atomicAdd(&gb[i1], -g1 * s1);
    atomicAdd(&gb[i2], -g2 * s2);

    outC[bm]   = C;
    outdxl[bm] = -alpha * (C - delta);
    outdxs[bm] = -beta * (xsv + eps) * (C - gamma);
}

extern "C" void kernel_launch(void* const* d_in, const int* in_sizes, int n_in,
                              void* d_out, int out_size, void* d_ws, size_t ws_size,
                              hipStream_t stream) {
    const float* v     = (const float*)d_in[0];
    const float* xl    = (const float*)d_in[1];
    const float* xs    = (const float*)d_in[2];
    const float* param = (const float*)d_in[3];
    const float* sign  = (const float*)d_in[4];
    const int*   idx   = (const int*)d_in[5];

    const int B = 128;
    const int N = in_sizes[0] / B;   // 20000
    const int M = in_sizes[1] / B;   // 85400

    float* outC   = (float*)d_out;
    float* gradv  = outC   + (size_t)in_sizes[1];
    float* outdxl = gradv  + (size_t)in_sizes[0];
    float* outdxs = outdxl + (size_t)in_sizes[1];

    const size_t bn = (size_t)B * N;
    const size_t ws_need = (size_t)BPB * bn * sizeof(float);

    if (N <= NMAX && ws_size >= ws_need && (bn % 4) == 0 && (M % 4) == 0) {
        float* partial = (float*)d_ws;
        // chunk: multiple of 4 so every group's base is 16B-aligned
        const int chunk = (((M + BPB - 1) / BPB) + 3) & ~3;
        or_priv4<<<dim3(BPB * B), dim3(1024), 0, stream>>>(
            v, xl, xs, param, sign, idx, outC, outdxl, outdxs,
            (float*)partial, N, M, B, chunk);
        const int n4 = (int)(bn / 4);
        const int rblocks = min(2048, (n4 + 255) / 256);
        reduce2<<<dim3(rblocks), dim3(256), 0, stream>>>(
            (const float4v*)partial, (float4v*)gradv, n4, n4);
    } else {
        const int n4 = (int)(bn / 4);
        zero_f4<<<dim3((n4 + 255) / 256), dim3(256), 0, stream>>>((float4v*)gradv, n4);
        dim3 grid((M + 255) / 256, B);
        or_kernel<<<grid, dim3(256), 0, stream>>>(v, xl, xs, param, sign, idx,
                                                  outC, gradv, outdxl, outdxs, N, M);
    }
}